// Round 8
// baseline (147.802 us; speedup 1.0000x reference)
//
#include <hip/hip_runtime.h>
#include <hip/hip_bf16.h>

typedef short v8s __attribute__((ext_vector_type(8)));
typedef float v16f __attribute__((ext_vector_type(16)));
typedef unsigned v2u __attribute__((ext_vector_type(2)));

#define F_ 128
#define K_ 512
#define M_ 65536
#define CH_SH 17408   // shorts per chunk table: Cb' 9216 (64c x 144f) + CT' 8192 (64c x 128f)
#define CB_OFF 9216

__device__ __forceinline__ short f2bf(float f) {
    union { float f; unsigned u; } v; v.f = f;
    unsigned u = v.u;
    u = (u + 0x7FFFu + ((u >> 16) & 1u)) >> 16;  // RNE
    return (short)u;
}
__device__ __forceinline__ float bf2f(short s) {
    union { float f; unsigned u; } v;
    v.u = ((unsigned)(unsigned short)s) << 16;
    return v.f;
}

#if __has_builtin(__builtin_amdgcn_permlane32_swap)
#define HAVE_PLS 1
#endif

// (a,b) -> (a.lo||b.lo, a.hi||b.hi): half-wave exchange for C->A layout (verified R4).
__device__ __forceinline__ void pswap(unsigned &a, unsigned &b, int lane) {
#ifdef HAVE_PLS
    v2u r = __builtin_amdgcn_permlane32_swap(a, b, false, false);
    a = (unsigned)r.x; b = (unsigned)r.y;
#else
    unsigned sa = (unsigned)__shfl_xor((int)a, 32);
    unsigned sb = (unsigned)__shfl_xor((int)b, 32);
    if (lane & 32) a = sb; else b = sa;
#endif
}

// Build combined per-chunk tables in fragment-granule order (verified R4/R6).
__global__ void prep_kernel(const float* __restrict__ centers, short* __restrict__ G) {
    const int c = blockIdx.x;     // 512 clusters
    const int f = threadIdx.x;    // 128 features
    const int ch = c >> 6, c64 = c & 63;
    const size_t base = (size_t)ch * CH_SH;
    float v = centers[c * F_ + f];
    short b = f2bf(v);
    float vb = bf2f(b);
    { const int ks = f >> 4, h = (f >> 3) & 1, j = f & 7;
      G[base + (size_t)((ks * 2 + h) * 64 + c64) * 8 + j] = b; }
    { const int kap = c64 >> 4, hh = (c64 >> 3) & 1, jj = c64 & 7;
      G[base + CB_OFF + (size_t)((kap * 2 + hh) * F_ + f) * 8 + jj] = b; }
    float s = vb * vb;
    #pragma unroll
    for (int off = 1; off < 64; off <<= 1) s += __shfl_xor(s, off);
    __shared__ float part[2];
    if ((f & 63) == 0) part[f >> 6] = s;
    __syncthreads();
    if (f < 16) {
        const float csq = part[0] + part[1];
        const float chv = -0.5f * csq;
        const short vh = f2bf(chv);
        const short vl = f2bf(chv - bf2f(vh));
        const short val = (f == 0) ? vh : (f == 1) ? vl : (f == 2) ? (short)0x3F80 : (short)0;
        const int h2 = f >> 3, j2 = f & 7;
        G[base + (size_t)((16 + h2) * 64 + c64) * 8 + j2] = val;
    }
}

// Epilogue for one 32-cluster half-tile: exp chain + pswap + PV MFMA.
// cf fragments read straight from global/L2 (coalesced 16 B/lane).
__device__ __forceinline__ void epi_ct(const v16f acc, const short* __restrict__ CTS, int ct,
                                       float& lden, v16f (&Of)[4], int h, int c32, int lane) {
    v8s cf[8];
    #pragma unroll
    for (int kp = 0; kp < 2; ++kp)
        #pragma unroll
        for (int ft = 0; ft < 4; ++ft)
            cf[kp * 4 + ft] = *(const v8s*)
                &CTS[(size_t)(((ct * 2 + kp) * 2 + h) * F_ + ft * 32 + c32) * 8];
    unsigned U[8];
    #pragma unroll
    for (int t = 0; t < 8; ++t) {
        const float d20 = fmaxf(-2.0f * acc[2 * t], 0.f);
        const float d21 = fmaxf(-2.0f * acc[2 * t + 1], 0.f);
        const float p0 = __expf(-__builtin_amdgcn_sqrtf(d20));
        const float p1 = __expf(-__builtin_amdgcn_sqrtf(d21));
        union { __hip_bfloat162 hh; unsigned u; } cv;
        cv.hh = __float22bfloat162_rn(make_float2(p0, p1));
        U[t] = cv.u;
        lden += __uint_as_float(cv.u << 16);        // denom from SAME rounded p
        lden += __uint_as_float(cv.u & 0xffff0000u);
    }
    #pragma unroll
    for (int kp = 0; kp < 2; ++kp) {
        unsigned s0 = U[4 * kp],     s2 = U[4 * kp + 2];
        unsigned s1 = U[4 * kp + 1], s3 = U[4 * kp + 3];
        pswap(s0, s2, lane);
        pswap(s1, s3, lane);
        union { v8s v; unsigned u[4]; } pf;
        pf.u[0] = s0; pf.u[1] = s1; pf.u[2] = s2; pf.u[3] = s3;
        #pragma unroll
        for (int ft = 0; ft < 4; ++ft)
            Of[ft] = __builtin_amdgcn_mfma_f32_32x32x16_bf16(pf.v, cf[kp * 4 + ft], Of[ft], 0, 0, 0);
    }
}

// R8 = R7 structure + full-depth L2 prefetch in stage 1. R7 counters pinned
// the cap: unified VGPR+AGPR file (~124 arch VGPR + ~96 acc regs) limits HW
// to 2 waves/SIMD regardless of grid (Occupancy stayed 16% with 2x the
// waves), so TLP is exhausted; the remaining hole is ILP. The old 2-deep
// sliding window stalled ~170 cyc on EVERY ks step (L2 ~200-300 cyc).
// New schedule per chunk: (1) issue all 9 chain-0 frags F0; (2) run the a0
// MFMA dep-chain (~290 cyc) while issuing the 9 chain-1 frags F1 in its
// shadow; (3) a1 chain sits in the same basic block as epi(a0)'s trans work
// (independent -> scheduler overlaps MFMA chain with sqrt/exp); (4) epi(a1).
// Exposed load stall drops to one ~250 cyc F0 wait per chunk. Register peak
// ~240-250 of the 256/wave available at 2 waves/SIMD; spill tripwire =
// FETCH/WRITE ballooning (R6 showed the signature).
__global__ __launch_bounds__(512, 2) void cluster_kernel(
        const float* __restrict__ x, const short* __restrict__ G,
        float* __restrict__ out) {
    __shared__ float MB[4][65][64];   // per-pair merge buffer: 64 Of + 1 lden
    const int tid = threadIdx.x;
    const int wave = tid >> 6, lane = tid & 63;
    const int s = wave & 1, p = wave >> 1;
    const int h = lane >> 5, c32 = lane & 31;
    const int row0 = blockIdx.x * 128 + p * 32;
    const int off = blockIdx.x & 7;

    // ---- x prologue: issue all 16 loads, then convert ----
    const float4* xr4 = (const float4*)(x + (size_t)(row0 + c32) * F_);
    float4 xl[16];
    #pragma unroll
    for (int ks = 0; ks < 8; ++ks) {
        xl[2 * ks]     = xr4[ks * 4 + h * 2];
        xl[2 * ks + 1] = xr4[ks * 4 + h * 2 + 1];
    }
    v8s Bx[9];
    float xs = 0.f;
    #pragma unroll
    for (int ks = 0; ks < 8; ++ks) {
        float vv[8] = {xl[2*ks].x, xl[2*ks].y, xl[2*ks].z, xl[2*ks].w,
                       xl[2*ks+1].x, xl[2*ks+1].y, xl[2*ks+1].z, xl[2*ks+1].w};
        v8s fr;
        #pragma unroll
        for (int j = 0; j < 8; ++j) {
            short bb = f2bf(vv[j]);
            fr[j] = bb;
            float r = bf2f(bb);
            xs += r * r;        // ||x~||^2 of bf16-rounded values
        }
        Bx[ks] = fr;
    }
    xs += __shfl_xor(xs, 32);
    {
        const float xh = -0.5f * xs;
        const short sxh = f2bf(xh);
        const short sxl = f2bf(xh - bf2f(sxh));
        v8s e = (v8s){0, 0, 0, 0, 0, 0, 0, 0};
        if (h == 0) { e[0] = (short)0x3F80; e[1] = (short)0x3F80; e[2] = sxh; e[3] = sxl; }
        Bx[8] = e;              // k=128..131 norm augmentation (verified R4)
    }

    v16f Of[4];
    #pragma unroll
    for (int ft = 0; ft < 4; ++ft)
        #pragma unroll
        for (int e2 = 0; e2 < 16; ++e2) Of[ft][e2] = 0.f;
    float lden = 0.f;

    // ---- 4 chunks per wave, straight from L2, no barriers ----
    #pragma unroll 1
    for (int j = 0; j < 4; ++j) {
        const int ch = (off + s * 4 + j) & 7;
        const short* Cb = G + (size_t)ch * CH_SH;

        // (1) full prefetch of chain-0 frags: 9 loads in flight.
        v8s F0[9];
        #pragma unroll
        for (int ks = 0; ks < 9; ++ks)
            F0[ks] = *(const v8s*)&Cb[(size_t)((ks * 2 + h) * 64 + c32) * 8];

        // (2) a0 dep-chain; F1 loads issued in its shadow (~290 cyc >= L2 lat).
        v16f a0, a1;
        #pragma unroll
        for (int e2 = 0; e2 < 16; ++e2) { a0[e2] = 0.f; a1[e2] = 0.f; }
        v8s F1[9];
        #pragma unroll
        for (int ks = 0; ks < 9; ++ks) {
            F1[ks] = *(const v8s*)&Cb[(size_t)((ks * 2 + h) * 64 + 32 + c32) * 8];
            a0 = __builtin_amdgcn_mfma_f32_32x32x16_bf16(F0[ks], Bx[ks], a0, 0, 0, 0);
        }

        // (3) a1 chain + epi(a0) in one BB: trans work overlaps the MFMA chain.
        #pragma unroll
        for (int ks = 0; ks < 9; ++ks)
            a1 = __builtin_amdgcn_mfma_f32_32x32x16_bf16(F1[ks], Bx[ks], a1, 0, 0, 0);
        epi_ct(a0, Cb + CB_OFF, 0, lden, Of, h, c32, lane);
        // (4)
        epi_ct(a1, Cb + CB_OFF, 1, lden, Of, h, c32, lane);
    }

    // ---- pair merge: odd wave publishes partials, even wave reduces ----
    if (s == 1) {
        #pragma unroll
        for (int ft = 0; ft < 4; ++ft)
            #pragma unroll
            for (int e2 = 0; e2 < 16; ++e2)
                MB[p][ft * 16 + e2][lane] = Of[ft][e2];
        MB[p][64][lane] = lden;
    }
    __syncthreads();
    if (s == 1) return;
    #pragma unroll
    for (int ft = 0; ft < 4; ++ft)
        #pragma unroll
        for (int e2 = 0; e2 < 16; ++e2)
            Of[ft][e2] += MB[p][ft * 16 + e2][lane];
    lden += MB[p][64][lane];

    // Denominator: lane sum covers all 512 clusters of row c32 after h-halves merge.
    lden += __shfl_xor(lden, 32);
    const float inv = 1.0f / lden;
    float invr[16];
    #pragma unroll
    for (int r = 0; r < 16; ++r)
        invr[r] = __shfl(inv, (r & 3) + 8 * (r >> 2) + 4 * h);
    #pragma unroll
    for (int ft = 0; ft < 4; ++ft)
        #pragma unroll
        for (int r = 0; r < 16; ++r) {
            const int xrow = (r & 3) + 8 * (r >> 2) + 4 * h;
            out[(size_t)(row0 + xrow) * F_ + ft * 32 + c32] = Of[ft][r] * invr[r];
        }
}

extern "C" void kernel_launch(void* const* d_in, const int* in_sizes, int n_in,
                              void* d_out, int out_size, void* d_ws, size_t ws_size,
                              hipStream_t stream) {
    const float* x       = (const float*)d_in[0];   // [8,8192,128] fp32
    const float* centers = (const float*)d_in[1];   // [512,128] fp32
    float* out = (float*)d_out;                     // [8,8192,128] fp32
    short* G = (short*)d_ws;                        // 8 chunks x 34816 B = 278528 B
    prep_kernel<<<K_, F_, 0, stream>>>(centers, G);
    cluster_kernel<<<M_ / 128, 512, 0, stream>>>(x, G, out);
}

// Round 9
// 146.339 us; speedup vs baseline: 1.0100x; 1.0100x over previous
//
#include <hip/hip_runtime.h>
#include <hip/hip_bf16.h>

typedef short v8s __attribute__((ext_vector_type(8)));
typedef float v16f __attribute__((ext_vector_type(16)));
typedef unsigned v2u __attribute__((ext_vector_type(2)));

#define F_ 128
#define K_ 512
#define M_ 65536
#define CH_SH 17408   // shorts per chunk table: Cb' 9216 (64c x 144f) + CT' 8192 (64c x 128f)
#define CB_OFF 9216

__device__ __forceinline__ short f2bf(float f) {
    union { float f; unsigned u; } v; v.f = f;
    unsigned u = v.u;
    u = (u + 0x7FFFu + ((u >> 16) & 1u)) >> 16;  // RNE
    return (short)u;
}
__device__ __forceinline__ float bf2f(short s) {
    union { float f; unsigned u; } v;
    v.u = ((unsigned)(unsigned short)s) << 16;
    return v.f;
}

#if __has_builtin(__builtin_amdgcn_permlane32_swap)
#define HAVE_PLS 1
#endif

// (a,b) -> (a.lo||b.lo, a.hi||b.hi): half-wave exchange for C->A layout (verified R4).
__device__ __forceinline__ void pswap(unsigned &a, unsigned &b, int lane) {
#ifdef HAVE_PLS
    v2u r = __builtin_amdgcn_permlane32_swap(a, b, false, false);
    a = (unsigned)r.x; b = (unsigned)r.y;
#else
    unsigned sa = (unsigned)__shfl_xor((int)a, 32);
    unsigned sb = (unsigned)__shfl_xor((int)b, 32);
    if (lane & 32) a = sb; else b = sa;
#endif
}

// Build combined per-chunk tables in fragment-granule order (verified R4/R6).
__global__ void prep_kernel(const float* __restrict__ centers, short* __restrict__ G) {
    const int c = blockIdx.x;     // 512 clusters
    const int f = threadIdx.x;    // 128 features
    const int ch = c >> 6, c64 = c & 63;
    const size_t base = (size_t)ch * CH_SH;
    float v = centers[c * F_ + f];
    short b = f2bf(v);
    float vb = bf2f(b);
    { const int ks = f >> 4, h = (f >> 3) & 1, j = f & 7;
      G[base + (size_t)((ks * 2 + h) * 64 + c64) * 8 + j] = b; }
    { const int kap = c64 >> 4, hh = (c64 >> 3) & 1, jj = c64 & 7;
      G[base + CB_OFF + (size_t)((kap * 2 + hh) * F_ + f) * 8 + jj] = b; }
    float s = vb * vb;
    #pragma unroll
    for (int off = 1; off < 64; off <<= 1) s += __shfl_xor(s, off);
    __shared__ float part[2];
    if ((f & 63) == 0) part[f >> 6] = s;
    __syncthreads();
    if (f < 16) {
        const float csq = part[0] + part[1];
        const float chv = -0.5f * csq;
        const short vh = f2bf(chv);
        const short vl = f2bf(chv - bf2f(vh));
        const short val = (f == 0) ? vh : (f == 1) ? vl : (f == 2) ? (short)0x3F80 : (short)0;
        const int h2 = f >> 3, j2 = f & 7;
        G[base + (size_t)((16 + h2) * 64 + c64) * 8 + j2] = val;
    }
}

// Stage 1 for one 64-cluster chunk, fragments straight from global/L2,
// DEPTH-3 sliding window (R9): issue-to-use gap of 3 steps, 6 live v8s.
// Gentle extension of the 2-deep form the compiler schedules well (the
// 9-deep explicit prefetch of R8 was sunk/rematerialized and regressed).
__device__ __forceinline__ void stage1_d3(const short* __restrict__ Cb, const v8s* Bx,
                                          v16f& a0, v16f& a1, int h, int c32) {
    #pragma unroll
    for (int e2 = 0; e2 < 16; ++e2) { a0[e2] = 0.f; a1[e2] = 0.f; }
    v8s w0[3], w1[3];
    #pragma unroll
    for (int i = 0; i < 3; ++i) {
        w0[i] = *(const v8s*)&Cb[(size_t)((i * 2 + h) * 64 + c32) * 8];
        w1[i] = *(const v8s*)&Cb[(size_t)((i * 2 + h) * 64 + 32 + c32) * 8];
    }
    #pragma unroll
    for (int ks = 0; ks < 9; ++ks) {        // full unroll -> ks%3 is static (no scratch)
        v8s c0 = w0[ks % 3], c1 = w1[ks % 3];
        if (ks < 6) {
            w0[ks % 3] = *(const v8s*)&Cb[(size_t)(((ks + 3) * 2 + h) * 64 + c32) * 8];
            w1[ks % 3] = *(const v8s*)&Cb[(size_t)(((ks + 3) * 2 + h) * 64 + 32 + c32) * 8];
        }
        a0 = __builtin_amdgcn_mfma_f32_32x32x16_bf16(c0, Bx[ks], a0, 0, 0, 0);
        a1 = __builtin_amdgcn_mfma_f32_32x32x16_bf16(c1, Bx[ks], a1, 0, 0, 0);
    }
}

// Epilogue for one 32-cluster half-tile: exp chain + pswap + PV MFMA.
// cf fragments read straight from global/L2 (coalesced 16 B/lane).
__device__ __forceinline__ void epi_ct(const v16f acc, const short* __restrict__ CTS, int ct,
                                       float& lden, v16f (&Of)[4], int h, int c32, int lane) {
    v8s cf[8];
    #pragma unroll
    for (int kp = 0; kp < 2; ++kp)
        #pragma unroll
        for (int ft = 0; ft < 4; ++ft)
            cf[kp * 4 + ft] = *(const v8s*)
                &CTS[(size_t)(((ct * 2 + kp) * 2 + h) * F_ + ft * 32 + c32) * 8];
    unsigned U[8];
    #pragma unroll
    for (int t = 0; t < 8; ++t) {
        const float d20 = fmaxf(-2.0f * acc[2 * t], 0.f);
        const float d21 = fmaxf(-2.0f * acc[2 * t + 1], 0.f);
        const float p0 = __expf(-__builtin_amdgcn_sqrtf(d20));
        const float p1 = __expf(-__builtin_amdgcn_sqrtf(d21));
        union { __hip_bfloat162 hh; unsigned u; } cv;
        cv.hh = __float22bfloat162_rn(make_float2(p0, p1));
        U[t] = cv.u;
        lden += __uint_as_float(cv.u << 16);        // denom from SAME rounded p
        lden += __uint_as_float(cv.u & 0xffff0000u);
    }
    #pragma unroll
    for (int kp = 0; kp < 2; ++kp) {
        unsigned s0 = U[4 * kp],     s2 = U[4 * kp + 2];
        unsigned s1 = U[4 * kp + 1], s3 = U[4 * kp + 3];
        pswap(s0, s2, lane);
        pswap(s1, s3, lane);
        union { v8s v; unsigned u[4]; } pf;
        pf.u[0] = s0; pf.u[1] = s1; pf.u[2] = s2; pf.u[3] = s3;
        #pragma unroll
        for (int ft = 0; ft < 4; ++ft)
            Of[ft] = __builtin_amdgcn_mfma_f32_32x32x16_bf16(pf.v, cf[kp * 4 + ft], Of[ft], 0, 0, 0);
    }
}

// R9 = R7 + depth-3 window + cross-chunk deferred epilogue. R8 showed the
// compiler vetoes 9-deep explicit prefetch (VGPR sank 124->84, loads
// rematerialized at use, cluster 44->76 us). R9 instead: (1) window depth
// 2->3 in the sliding form the compiler handles; (2) epilogue of chunk j-1
// placed in the SAME basic block as stage1 of chunk j (R2's pipeline,
// transplanted to the no-barrier L2-direct structure where its mechanism can
// act: ~1.2K cyc of independent trans/VALU work fills stage1's L2 load-stall
// shadows; TLP is pinned at 2 waves/SIMD by the unified register file, so
// ILP is the only cover). lden/Of accumulation order unchanged -> identical
// numerics. Register peak ~240 <= 256 at 2 waves/SIMD; spill tripwire =
// FETCH/WRITE ballooning.
__global__ __launch_bounds__(512, 2) void cluster_kernel(
        const float* __restrict__ x, const short* __restrict__ G,
        float* __restrict__ out) {
    __shared__ float MB[4][65][64];   // per-pair merge buffer: 64 Of + 1 lden
    const int tid = threadIdx.x;
    const int wave = tid >> 6, lane = tid & 63;
    const int s = wave & 1, p = wave >> 1;
    const int h = lane >> 5, c32 = lane & 31;
    const int row0 = blockIdx.x * 128 + p * 32;
    const int off = blockIdx.x & 7;

    // ---- x prologue: issue all 16 loads, then convert ----
    const float4* xr4 = (const float4*)(x + (size_t)(row0 + c32) * F_);
    float4 xl[16];
    #pragma unroll
    for (int ks = 0; ks < 8; ++ks) {
        xl[2 * ks]     = xr4[ks * 4 + h * 2];
        xl[2 * ks + 1] = xr4[ks * 4 + h * 2 + 1];
    }
    v8s Bx[9];
    float xs = 0.f;
    #pragma unroll
    for (int ks = 0; ks < 8; ++ks) {
        float vv[8] = {xl[2*ks].x, xl[2*ks].y, xl[2*ks].z, xl[2*ks].w,
                       xl[2*ks+1].x, xl[2*ks+1].y, xl[2*ks+1].z, xl[2*ks+1].w};
        v8s fr;
        #pragma unroll
        for (int j = 0; j < 8; ++j) {
            short bb = f2bf(vv[j]);
            fr[j] = bb;
            float r = bf2f(bb);
            xs += r * r;        // ||x~||^2 of bf16-rounded values
        }
        Bx[ks] = fr;
    }
    xs += __shfl_xor(xs, 32);
    {
        const float xh = -0.5f * xs;
        const short sxh = f2bf(xh);
        const short sxl = f2bf(xh - bf2f(sxh));
        v8s e = (v8s){0, 0, 0, 0, 0, 0, 0, 0};
        if (h == 0) { e[0] = (short)0x3F80; e[1] = (short)0x3F80; e[2] = sxh; e[3] = sxl; }
        Bx[8] = e;              // k=128..131 norm augmentation (verified R4)
    }

    v16f Of[4];
    #pragma unroll
    for (int ft = 0; ft < 4; ++ft)
        #pragma unroll
        for (int e2 = 0; e2 < 16; ++e2) Of[ft][e2] = 0.f;
    float lden = 0.f;

    // ---- peeled chunk 0: stage1 only, epilogue deferred ----
    v16f a0p, a1p;
    const short* prevCT;
    {
        const short* Cb = G + (size_t)((off + s * 4) & 7) * CH_SH;
        stage1_d3(Cb, Bx, a0p, a1p, h, c32);
        prevCT = Cb + CB_OFF;
    }

    #pragma unroll 1
    for (int j = 1; j < 4; ++j) {
        const short* Cb = G + (size_t)((off + s * 4 + j) & 7) * CH_SH;
        v16f a0, a1;
        stage1_d3(Cb, Bx, a0, a1, h, c32);          // chunk j (L2 loads + MFMA)
        epi_ct(a0p, prevCT, 0, lden, Of, h, c32, lane);   // chunk j-1 epilogue
        epi_ct(a1p, prevCT, 1, lden, Of, h, c32, lane);   //  (trans/VALU fills stalls)
        a0p = a0; a1p = a1;
        prevCT = Cb + CB_OFF;
    }
    // ---- tail: epilogue of the last chunk ----
    epi_ct(a0p, prevCT, 0, lden, Of, h, c32, lane);
    epi_ct(a1p, prevCT, 1, lden, Of, h, c32, lane);

    // ---- pair merge: odd wave publishes partials, even wave reduces ----
    if (s == 1) {
        #pragma unroll
        for (int ft = 0; ft < 4; ++ft)
            #pragma unroll
            for (int e2 = 0; e2 < 16; ++e2)
                MB[p][ft * 16 + e2][lane] = Of[ft][e2];
        MB[p][64][lane] = lden;
    }
    __syncthreads();
    if (s == 1) return;
    #pragma unroll
    for (int ft = 0; ft < 4; ++ft)
        #pragma unroll
        for (int e2 = 0; e2 < 16; ++e2)
            Of[ft][e2] += MB[p][ft * 16 + e2][lane];
    lden += MB[p][64][lane];

    // Denominator: lane sum covers all 512 clusters of row c32 after h-halves merge.
    lden += __shfl_xor(lden, 32);
    const float inv = 1.0f / lden;
    float invr[16];
    #pragma unroll
    for (int r = 0; r < 16; ++r)
        invr[r] = __shfl(inv, (r & 3) + 8 * (r >> 2) + 4 * h);
    #pragma unroll
    for (int ft = 0; ft < 4; ++ft)
        #pragma unroll
        for (int r = 0; r < 16; ++r) {
            const int xrow = (r & 3) + 8 * (r >> 2) + 4 * h;
            out[(size_t)(row0 + xrow) * F_ + ft * 32 + c32] = Of[ft][r] * invr[r];
        }
}

extern "C" void kernel_launch(void* const* d_in, const int* in_sizes, int n_in,
                              void* d_out, int out_size, void* d_ws, size_t ws_size,
                              hipStream_t stream) {
    const float* x       = (const float*)d_in[0];   // [8,8192,128] fp32
    const float* centers = (const float*)d_in[1];   // [512,128] fp32
    float* out = (float*)d_out;                     // [8,8192,128] fp32
    short* G = (short*)d_ws;                        // 8 chunks x 34816 B = 278528 B
    prep_kernel<<<K_, F_, 0, stream>>>(centers, G);
    cluster_kernel<<<M_ / 128, 512, 0, stream>>>(x, G, out);
}

// Round 10
// 102.918 us; speedup vs baseline: 1.4361x; 1.4219x over previous
//
#include <hip/hip_runtime.h>
#include <hip/hip_bf16.h>

typedef short v8s __attribute__((ext_vector_type(8)));
typedef float v16f __attribute__((ext_vector_type(16)));
typedef unsigned v2u __attribute__((ext_vector_type(2)));

#define F_ 128
#define K_ 512
#define M_ 65536
#define CH_SH 17408   // shorts per chunk table: Cb' 9216 (64c x 144f) + CT' 8192 (64c x 128f)
#define CB_OFF 9216

typedef __attribute__((address_space(1))) const char gch;
typedef __attribute__((address_space(3))) char lch;

__device__ __forceinline__ short f2bf(float f) {
    union { float f; unsigned u; } v; v.f = f;
    unsigned u = v.u;
    u = (u + 0x7FFFu + ((u >> 16) & 1u)) >> 16;  // RNE
    return (short)u;
}
__device__ __forceinline__ float bf2f(short s) {
    union { float f; unsigned u; } v;
    v.u = ((unsigned)(unsigned short)s) << 16;
    return v.f;
}

#if __has_builtin(__builtin_amdgcn_permlane32_swap)
#define HAVE_PLS 1
#endif

// (a,b) -> (a.lo||b.lo, a.hi||b.hi): half-wave exchange for C->A layout (verified R4).
__device__ __forceinline__ void pswap(unsigned &a, unsigned &b, int lane) {
#ifdef HAVE_PLS
    v2u r = __builtin_amdgcn_permlane32_swap(a, b, false, false);
    a = (unsigned)r.x; b = (unsigned)r.y;
#else
    unsigned sa = (unsigned)__shfl_xor((int)a, 32);
    unsigned sb = (unsigned)__shfl_xor((int)b, 32);
    if (lane & 32) a = sb; else b = sa;
#endif
}

// Build combined per-chunk tables in fragment-granule order (verified R4/R6).
__global__ void prep_kernel(const float* __restrict__ centers, short* __restrict__ G) {
    const int c = blockIdx.x;     // 512 clusters
    const int f = threadIdx.x;    // 128 features
    const int ch = c >> 6, c64 = c & 63;
    const size_t base = (size_t)ch * CH_SH;
    float v = centers[c * F_ + f];
    short b = f2bf(v);
    float vb = bf2f(b);
    { const int ks = f >> 4, h = (f >> 3) & 1, j = f & 7;
      G[base + (size_t)((ks * 2 + h) * 64 + c64) * 8 + j] = b; }
    { const int kap = c64 >> 4, hh = (c64 >> 3) & 1, jj = c64 & 7;
      G[base + CB_OFF + (size_t)((kap * 2 + hh) * F_ + f) * 8 + jj] = b; }
    float s = vb * vb;
    #pragma unroll
    for (int off = 1; off < 64; off <<= 1) s += __shfl_xor(s, off);
    __shared__ float part[2];
    if ((f & 63) == 0) part[f >> 6] = s;
    __syncthreads();
    if (f < 16) {
        const float csq = part[0] + part[1];
        const float chv = -0.5f * csq;
        const short vh = f2bf(chv);
        const short vl = f2bf(chv - bf2f(vh));
        const short val = (f == 0) ? vh : (f == 1) ? vl : (f == 2) ? (short)0x3F80 : (short)0;
        const int h2 = f >> 3, j2 = f & 7;
        G[base + (size_t)((16 + h2) * 64 + c64) * 8 + j2] = val;
    }
}

// Linear 34 KB chunk copy (2176 granules) via async DMA, 512 threads (8 waves).
__device__ __forceinline__ void stage_chunk(const short* __restrict__ G, short* dst,
                                            int ch, int wave, int lane) {
    const char* src = (const char*)(G + (size_t)ch * CH_SH);
    lch* d = (lch*)dst;
    #pragma unroll
    for (int t = 0; t < 4; ++t) {
        const int g = t * 512 + wave * 64 + lane;
        __builtin_amdgcn_global_load_lds((gch*)(src + (size_t)g * 16),
                                         d + (size_t)(t * 512 + wave * 64) * 16, 16, 0, 0);
    }
    if (wave < 2) {
        const int g = 2048 + wave * 64 + lane;
        __builtin_amdgcn_global_load_lds((gch*)(src + (size_t)g * 16),
                                         d + (size_t)(2048 + wave * 64) * 16, 16, 0, 0);
    }
}

// Stage 1 for one 64-cluster chunk: two independent MFMA chains over a sliding
// 2-deep A-frag window. a0 = clusters [0,32), a1 = [32,64) of the chunk.
__device__ __forceinline__ void stage1(const short* CbS, const v8s* Bx,
                                       v16f& a0, v16f& a1, int h, int c32) {
    #pragma unroll
    for (int e2 = 0; e2 < 16; ++e2) { a0[e2] = 0.f; a1[e2] = 0.f; }
    v8s f0a = *(const v8s*)&CbS[(size_t)((0 * 2 + h) * 64 + c32) * 8];
    v8s f1a = *(const v8s*)&CbS[(size_t)((0 * 2 + h) * 64 + 32 + c32) * 8];
    v8s f0b = *(const v8s*)&CbS[(size_t)((1 * 2 + h) * 64 + c32) * 8];
    v8s f1b = *(const v8s*)&CbS[(size_t)((1 * 2 + h) * 64 + 32 + c32) * 8];
    #pragma unroll
    for (int ks = 0; ks < 9; ++ks) {
        v8s c0 = f0a, c1 = f1a;
        f0a = f0b; f1a = f1b;
        if (ks < 7) {
            f0b = *(const v8s*)&CbS[(size_t)(((ks + 2) * 2 + h) * 64 + c32) * 8];
            f1b = *(const v8s*)&CbS[(size_t)(((ks + 2) * 2 + h) * 64 + 32 + c32) * 8];
        }
        a0 = __builtin_amdgcn_mfma_f32_32x32x16_bf16(c0, Bx[ks], a0, 0, 0, 0);
        a1 = __builtin_amdgcn_mfma_f32_32x32x16_bf16(c1, Bx[ks], a1, 0, 0, 0);
    }
}

// Deferred epilogue for one 32-cluster half-tile: exp chain + pswap + PV MFMA.
// lden accumulation order matches the original (ct0 then ct1 per chunk, chunks
// in order) so results stay bit-identical.
__device__ __forceinline__ void epi_ct(const v16f acc, const short* CTS, int ct,
                                       float& lden, v16f (&Of)[4], int h, int c32, int lane) {
    v8s cf[8];
    #pragma unroll
    for (int kp = 0; kp < 2; ++kp)
        #pragma unroll
        for (int ft = 0; ft < 4; ++ft)
            cf[kp * 4 + ft] = *(const v8s*)
                &CTS[(size_t)(((ct * 2 + kp) * 2 + h) * F_ + ft * 32 + c32) * 8];
    unsigned U[8];
    #pragma unroll
    for (int t = 0; t < 8; ++t) {
        const float d20 = fmaxf(-2.0f * acc[2 * t], 0.f);
        const float d21 = fmaxf(-2.0f * acc[2 * t + 1], 0.f);
        const float p0 = __expf(-__builtin_amdgcn_sqrtf(d20));
        const float p1 = __expf(-__builtin_amdgcn_sqrtf(d21));
        union { __hip_bfloat162 hh; unsigned u; } cv;
        cv.hh = __float22bfloat162_rn(make_float2(p0, p1));
        U[t] = cv.u;
        lden += __uint_as_float(cv.u << 16);        // denom from SAME rounded p
        lden += __uint_as_float(cv.u & 0xffff0000u);
    }
    #pragma unroll
    for (int kp = 0; kp < 2; ++kp) {
        unsigned s0 = U[4 * kp],     s2 = U[4 * kp + 2];
        unsigned s1 = U[4 * kp + 1], s3 = U[4 * kp + 3];
        pswap(s0, s2, lane);
        pswap(s1, s3, lane);
        union { v8s v; unsigned u[4]; } pf;
        pf.u[0] = s0; pf.u[1] = s1; pf.u[2] = s2; pf.u[3] = s3;
        #pragma unroll
        for (int ft = 0; ft < 4; ++ft)
            Of[ft] = __builtin_amdgcn_mfma_f32_32x32x16_bf16(pf.v, cf[kp * 4 + ft], Of[ft], 0, 0, 0);
    }
}

// FINAL (session close-out, reversion to best): 512-thread blocks (8 waves x
// 32 rows), grid 256 = 1 block/CU, triple-buffered 64c chunks (102 KB LDS),
// cross-chunk software pipeline (stage1 of chunk j + deferred epilogue of
// chunk j-1 in one straight-line BB). Measured dur 103.075 / 104.507 us
// (cluster ~45.5 us) - best of 10 rounds. Counter-backed session findings:
// occupancy pinned at 2 waves/SIMD by unified VGPR+AGPR file (R6/R7);
// latency-bound, all pipes <=31% (R5/R7); deeper source-level prefetch is
// compiler-vetoed and regresses 1.7-1.8x (R8/R9); LDS-path == L2-path within
// noise (R5 vs R7). ~60 us of dur_us is fixed harness work (256 MiB poison
// fill ~42.5 us + prep + restores).
__global__ __launch_bounds__(512, 2) void cluster_kernel(
        const float* __restrict__ x, const short* __restrict__ G,
        float* __restrict__ out) {
    __shared__ __align__(16) short SB[3][CH_SH];   // 3 x 34 KB rotating buffers
    const int tid = threadIdx.x;
    const int wave = tid >> 6, lane = tid & 63;
    const int h = lane >> 5, c32 = lane & 31;
    const int row0 = blockIdx.x * 256 + wave * 32;

    short* const SB0 = &SB[0][0];
    const int off = blockIdx.x & 7;
    stage_chunk(G, SB0, off, wave, lane);          // chunk0 -> buf0 (drains below)

    // ---- x prologue: issue all 16 loads, then convert ----
    const float4* xr4 = (const float4*)(x + (size_t)(row0 + c32) * F_);
    float4 xl[16];
    #pragma unroll
    for (int ks = 0; ks < 8; ++ks) {
        xl[2 * ks]     = xr4[ks * 4 + h * 2];
        xl[2 * ks + 1] = xr4[ks * 4 + h * 2 + 1];
    }
    v8s Bx[9];
    float xs = 0.f;
    #pragma unroll
    for (int ks = 0; ks < 8; ++ks) {
        float vv[8] = {xl[2*ks].x, xl[2*ks].y, xl[2*ks].z, xl[2*ks].w,
                       xl[2*ks+1].x, xl[2*ks+1].y, xl[2*ks+1].z, xl[2*ks+1].w};
        v8s fr;
        #pragma unroll
        for (int j = 0; j < 8; ++j) {
            short bb = f2bf(vv[j]);
            fr[j] = bb;
            float r = bf2f(bb);
            xs += r * r;        // ||x~||^2 of bf16-rounded values
        }
        Bx[ks] = fr;
    }
    xs += __shfl_xor(xs, 32);
    {
        const float xh = -0.5f * xs;
        const short sxh = f2bf(xh);
        const short sxl = f2bf(xh - bf2f(sxh));
        v8s e = (v8s){0, 0, 0, 0, 0, 0, 0, 0};
        if (h == 0) { e[0] = (short)0x3F80; e[1] = (short)0x3F80; e[2] = sxh; e[3] = sxl; }
        Bx[8] = e;              // k=128..131 norm augmentation (verified R4)
    }

    v16f Of[4];
    #pragma unroll
    for (int ft = 0; ft < 4; ++ft)
        #pragma unroll
        for (int e2 = 0; e2 < 16; ++e2) Of[ft][e2] = 0.f;
    float lden = 0.f;

    // ---- peeled j=0: stage-1 only, epilogue deferred into the loop ----
    __syncthreads();                               // drain chunk0 staging
    stage_chunk(G, SB0 + CH_SH, (off + 1) & 7, wave, lane);   // chunk1 -> buf1
    v16f a0p, a1p;
    stage1(SB0, Bx, a0p, a1p, h, c32);
    const short* prevCTS = SB0 + CB_OFF;

    #pragma unroll 1
    for (int j = 1; j < 8; ++j) {
        __syncthreads();        // chunk j staged >= one body ago: ~free drain.
                                // Also fences: epilogue(j-2) reads of buf (j+1)%3
                                // finished before this barrier, so restaging it
                                // below is race-free.
        if (j < 7)
            stage_chunk(G, SB0 + (size_t)((j + 1) % 3) * CH_SH, (off + j + 1) & 7, wave, lane);
        const short* CbS = SB0 + (size_t)(j % 3) * CH_SH;
        v16f a0, a1;
        stage1(CbS, Bx, a0, a1, h, c32);           // chunk j distances (LDS+MFMA)
        epi_ct(a0p, prevCTS, 0, lden, Of, h, c32, lane);  // chunk j-1 epilogue
        epi_ct(a1p, prevCTS, 1, lden, Of, h, c32, lane);  //   (trans+VALU+PV MFMA)
        a0p = a0; a1p = a1;
        prevCTS = CbS + CB_OFF;
    }
    // ---- tail: epilogue of chunk 7 ----
    epi_ct(a0p, prevCTS, 0, lden, Of, h, c32, lane);
    epi_ct(a1p, prevCTS, 1, lden, Of, h, c32, lane);

    // Denominator: lane sum covers all 512 clusters of row c32 after h-halves merge.
    lden += __shfl_xor(lden, 32);
    const float inv = 1.0f / lden;
    float invr[16];
    #pragma unroll
    for (int r = 0; r < 16; ++r)
        invr[r] = __shfl(inv, (r & 3) + 8 * (r >> 2) + 4 * h);
    #pragma unroll
    for (int ft = 0; ft < 4; ++ft)
        #pragma unroll
        for (int r = 0; r < 16; ++r) {
            const int xrow = (r & 3) + 8 * (r >> 2) + 4 * h;
            out[(size_t)(row0 + xrow) * F_ + ft * 32 + c32] = Of[ft][r] * invr[r];
        }
}

extern "C" void kernel_launch(void* const* d_in, const int* in_sizes, int n_in,
                              void* d_out, int out_size, void* d_ws, size_t ws_size,
                              hipStream_t stream) {
    const float* x       = (const float*)d_in[0];   // [8,8192,128] fp32
    const float* centers = (const float*)d_in[1];   // [512,128] fp32
    float* out = (float*)d_out;                     // [8,8192,128] fp32
    short* G = (short*)d_ws;                        // 8 chunks x 34816 B = 278528 B
    prep_kernel<<<K_, F_, 0, stream>>>(centers, G);
    cluster_kernel<<<M_ / 256, 512, 0, stream>>>(x, G, out);
}